// Round 3
// baseline (442.027 us; speedup 1.0000x reference)
//
#include <hip/hip_runtime.h>

typedef unsigned short u16;
typedef __attribute__((ext_vector_type(8))) short short8;
typedef __attribute__((ext_vector_type(4))) float f32x4;

__device__ __forceinline__ float bf2f(u16 u){ return __uint_as_float(((unsigned)u)<<16); }
__device__ __forceinline__ u16 f2bf(float f){
  unsigned u = __float_as_uint(f);
  unsigned r = u + 0x7fffu + ((u>>16)&1u);   // RNE (no NaN/inf in this problem)
  return (u16)(r>>16);
}

#define MFMA16(a,b,c) __builtin_amdgcn_mfma_f32_16x16x32_bf16(a,b,c,0,0,0)

// ---- LDS layout (u16 element offsets). Strides padded to 264/72 (2-way bank
// aliasing = free per m136; 256/64 would be 16-way). Total 113,664 B.
static constexpr int XS_STR  = 264;
static constexpr int PS_STR  = 72;
static constexpr int WT_STR  = 72;
static constexpr int XHI_OFF = 0;         // 64x264 = 16896
static constexpr int XLO_OFF = 16896;     // 64x264
static constexpr int GW_OFF  = 33792;     // shared in time: Gt 64x264 / Wt 256x72=18432
static constexpr int PS_OFF  = 52224;     // 64x72 = 4608
static constexpr int SMEM_U16 = 56832;
static constexpr int SMEM_BYTES = SMEM_U16*2;   // 113664

// ---- ws layout (u16 elems): MhT_hi[8*65536] | MhT_lo[8*65536] | vT[65536] | so[2048 f32]
// total 2,236,416 bytes

// MhT[h][d'][d] = Mh[d][d'] = sum_ko q[h][d][ko]*k[d'][ko]   (exact fp32, then hi/lo bf16)
__global__ void mh_kernel(const float* __restrict__ q, const float* __restrict__ k,
                          u16* __restrict__ mhi, u16* __restrict__ mlo){
  int blk = blockIdx.x;                 // 2048 = 8 heads * 256 d'
  int h = blk >> 8, dp = blk & 255;
  int t = threadIdx.x;                  // t = d
  const float* qrow = q + (h*256 + t)*256;
  const float* krow = k + dp*256;       // uniform per block -> scalarized
  float s = 0.f;
  for (int ko=0;ko<256;ko++) s = fmaf(qrow[ko], krow[ko], s);
  int off = (h*256 + dp)*256 + t;
  u16 hi = f2bf(s);
  mhi[off] = hi;
  mlo[off] = f2bf(s - bf2f(hi));
}

// vT[vout][d] = bf16(v[d][vout])
__global__ void vt_kernel(const float* __restrict__ v, u16* __restrict__ vT){
  int e = blockIdx.x*256 + threadIdx.x;  // 65536
  int r = e >> 8, c = e & 255;
  vT[e] = f2bf(v[c*256 + r]);
}

// so[h][d] = sum_v o[h][d][v]  (fp32)
__global__ void so_kernel(const float* __restrict__ o, float* __restrict__ so){
  int h = blockIdx.x, d = threadIdx.x;   // 8 x 256
  const float* row = o + (h*256 + d)*256;
  float s = 0.f;
  for (int e=0;e<256;e++) s += row[e];
  so[h*256 + d] = s;
}

// BR=0: per-(b,y) column attention over m, heads 0..3, overwrites out.
// BR=1: per-(b,x) row attention over n, heads 4..7, accumulates into out.
template<int BR>
__global__ __launch_bounds__(256,1) void attn_kernel(
    const float* __restrict__ x, const u16* __restrict__ mhiP,
    const u16* __restrict__ mloP, const u16* __restrict__ vT,
    const float* __restrict__ soP, float* __restrict__ out)
{
  extern __shared__ u16 sm[];
  u16* Xhi = sm + XHI_OFF;
  u16* Xlo = sm + XLO_OFF;
  u16* Gt  = sm + GW_OFF;     // G hi/lo staging (alive: G write -> logits)
  u16* Wt  = sm + GW_OFF;     // Wh^T 256x72   (alive: Wh write -> Z-mm)
  u16* Ps  = sm + PS_OFF;

  const int tid  = threadIdx.x;
  const int w    = tid >> 6, lane = tid & 63;
  const int quad = lane >> 4, m16 = lane & 15;
  const int b    = blockIdx.x >> 6, s = blockIdx.x & 63;
  const int cw   = w << 6;
  const int koq  = quad << 3;

  // flat element offset of token t's row in x/out
  auto tok = [&](int t)->int {
    int m = (BR==0) ? t : s;
    int n = (BR==0) ? s : t;
    return (((b<<6) + m) << 14) + (n << 8);
  };

  // ---- stage X (64 tokens x 256 fp32) -> Xhi/Xlo bf16 in LDS
  #pragma unroll
  for (int i=0;i<16;i++){
    int idx4 = i*256 + tid;              // float4 units, 4096 total
    int tr = idx4 >> 6, c4 = idx4 & 63;
    const float4 xv = *(const float4*)(x + tok(tr) + (c4<<2));
    ushort4 hv, lv;
    float f0=xv.x, f1=xv.y, f2=xv.z, f3=xv.w;
    hv.x=f2bf(f0); lv.x=f2bf(f0-bf2f(hv.x));
    hv.y=f2bf(f1); lv.y=f2bf(f1-bf2f(hv.y));
    hv.z=f2bf(f2); lv.z=f2bf(f2-bf2f(hv.z));
    hv.w=f2bf(f3); lv.w=f2bf(f3-bf2f(hv.w));
    *(ushort4*)&Xhi[tr*XS_STR + (c4<<2)] = hv;
    *(ushort4*)&Xlo[tr*XS_STR + (c4<<2)] = lv;
  }
  __syncthreads();

  const f32x4 zf = {0.f,0.f,0.f,0.f};
  f32x4 acc[4][4];

  // acc = Xhi@Whi + Xhi@Wlo + Xlo@Whi  (W row-major transposed-weight [n][k], global)
  auto mm3 = [&](const u16* __restrict__ Whi, const u16* __restrict__ Wlo){
    #pragma unroll
    for (int r=0;r<4;r++)
      #pragma unroll
      for (int c=0;c<4;c++) acc[r][c] = zf;
    for (int kk=0;kk<8;kk++){
      const int ko = (kk<<5) + koq;
      short8 Ah[4], Al[4], Bh[4], Bl[4];
      #pragma unroll
      for (int r=0;r<4;r++) Ah[r] = *(const short8*)&Xhi[(r*16+m16)*XS_STR + ko];
      #pragma unroll
      for (int r=0;r<4;r++) Al[r] = *(const short8*)&Xlo[(r*16+m16)*XS_STR + ko];
      #pragma unroll
      for (int c=0;c<4;c++) Bh[c] = *(const short8*)&Whi[(cw + c*16 + m16)*256 + ko];
      #pragma unroll
      for (int c=0;c<4;c++) Bl[c] = *(const short8*)&Wlo[(cw + c*16 + m16)*256 + ko];
      #pragma unroll
      for (int r=0;r<4;r++)
        #pragma unroll
        for (int c=0;c<4;c++){
          acc[r][c] = MFMA16(Ah[r], Bh[c], acc[r][c]);
          acc[r][c] = MFMA16(Ah[r], Bl[c], acc[r][c]);
          acc[r][c] = MFMA16(Al[r], Bh[c], acc[r][c]);
        }
    }
  };

  // acc = Xhi@W  (single term; used for Wh = X@v)
  auto mm1 = [&](const u16* __restrict__ Wg){
    #pragma unroll
    for (int r=0;r<4;r++)
      #pragma unroll
      for (int c=0;c<4;c++) acc[r][c] = zf;
    for (int kk=0;kk<8;kk++){
      const int ko = (kk<<5) + koq;
      short8 A[4], Bf[4];
      #pragma unroll
      for (int r=0;r<4;r++) A[r]  = *(const short8*)&Xhi[(r*16+m16)*XS_STR + ko];
      #pragma unroll
      for (int c=0;c<4;c++) Bf[c] = *(const short8*)&Wg[(cw + c*16 + m16)*256 + ko];
      #pragma unroll
      for (int r=0;r<4;r++)
        #pragma unroll
        for (int c=0;c<4;c++) acc[r][c] = MFMA16(A[r], Bf[c], acc[r][c]);
    }
  };

  f32x4 Z[4][4];
  #pragma unroll
  for (int r=0;r<4;r++)
    #pragma unroll
    for (int c=0;c<4;c++) Z[r][c] = zf;

  for (int h=0; h<4; h++){
    const int gh = BR*4 + h;

    // ---- G = X @ Mh[gh]  (3-term hi/lo), keep fp32 acc live; write Ghi
    mm3(mhiP + gh*65536, mloP + gh*65536);
    #pragma unroll
    for (int r=0;r<4;r++)
      #pragma unroll
      for (int c=0;c<4;c++)
        #pragma unroll
        for (int g=0; g<4; g++){
          int row = r*16 + quad*4 + g;
          int col = cw + c*16 + m16;
          Gt[row*XS_STR + col] = f2bf(acc[r][c][g]);
        }
    __syncthreads();

    // ---- logits phase A: Ghi@Xhi^T + Ghi@Xlo^T. Wave owns rows w*16..+16.
    f32x4 L[4];
    #pragma unroll
    for (int c=0;c<4;c++) L[c] = zf;
    for (int kk=0;kk<8;kk++){
      const int ko = (kk<<5) + koq;
      short8 A = *(const short8*)&Gt[(w*16+m16)*XS_STR + ko];
      #pragma unroll
      for (int c=0;c<4;c++)
        L[c] = MFMA16(A, *(const short8*)&Xhi[(c*16+m16)*XS_STR + ko], L[c]);
      #pragma unroll
      for (int c=0;c<4;c++)
        L[c] = MFMA16(A, *(const short8*)&Xlo[(c*16+m16)*XS_STR + ko], L[c]);
    }
    __syncthreads();
    // write Glo from retained acc
    #pragma unroll
    for (int r=0;r<4;r++)
      #pragma unroll
      for (int c=0;c<4;c++)
        #pragma unroll
        for (int g=0; g<4; g++){
          int row = r*16 + quad*4 + g;
          int col = cw + c*16 + m16;
          float vv = acc[r][c][g];
          u16 hh = f2bf(vv);
          Gt[row*XS_STR + col] = f2bf(vv - bf2f(hh));
        }
    __syncthreads();
    // ---- logits phase B: Glo@Xhi^T
    for (int kk=0;kk<8;kk++){
      const int ko = (kk<<5) + koq;
      short8 A = *(const short8*)&Gt[(w*16+m16)*XS_STR + ko];
      #pragma unroll
      for (int c=0;c<4;c++)
        L[c] = MFMA16(A, *(const short8*)&Xhi[(c*16+m16)*XS_STR + ko], L[c]);
    }

    // ---- softmax over z. Row = w*16+quad*4+g; its 64 values live in the 16
    // lanes of this quad across 4 c-tiles; xor masks <16 stay in-quad.
    #pragma unroll
    for (int g=0; g<4; g++){
      float mx = fmaxf(fmaxf(L[0][g],L[1][g]), fmaxf(L[2][g],L[3][g]));
      #pragma unroll
      for (int off=1; off<16; off<<=1) mx = fmaxf(mx, __shfl_xor(mx, off, 64));
      float sum = 0.f;
      #pragma unroll
      for (int c=0;c<4;c++){ float e = __expf(L[c][g]-mx); L[c][g] = e; sum += e; }
      #pragma unroll
      for (int off=1; off<16; off<<=1) sum += __shfl_xor(sum, off, 64);
      float inv = 1.f / sum;
      int row = w*16 + quad*4 + g;
      #pragma unroll
      for (int c=0;c<4;c++) Ps[row*PS_STR + c*16 + m16] = f2bf(L[c][g]*inv);
    }
    __syncthreads();   // Ps visible; all Gt reads done -> Wt may overwrite

    // ---- Wh = (X @ v) * so[gh][col], write transposed (256 x 64)
    mm1(vT);
    float sc[4];
    #pragma unroll
    for (int c=0;c<4;c++) sc[c] = soP[gh*256 + cw + c*16 + m16];
    #pragma unroll
    for (int r=0;r<4;r++)
      #pragma unroll
      for (int c=0;c<4;c++)
        #pragma unroll
        for (int g=0; g<4; g++){
          int z  = r*16 + quad*4 + g;
          int vc = cw + c*16 + m16;
          Wt[vc*WT_STR + z] = f2bf(acc[r][c][g] * sc[c]);
        }
    __syncthreads();

    // ---- Z += P @ WhT^T   (K-dim = 64 tokens -> 2 ksteps)
    #pragma unroll
    for (int kk=0;kk<2;kk++){
      const int ko = (kk<<5) + koq;
      short8 A[4], Bf[4];
      #pragma unroll
      for (int r=0;r<4;r++) A[r]  = *(const short8*)&Ps[(r*16+m16)*PS_STR + ko];
      #pragma unroll
      for (int c=0;c<4;c++) Bf[c] = *(const short8*)&Wt[(cw + c*16 + m16)*WT_STR + ko];
      #pragma unroll
      for (int r=0;r<4;r++)
        #pragma unroll
        for (int c=0;c<4;c++) Z[r][c] = MFMA16(A[r], Bf[c], Z[r][c]);
    }
    __syncthreads();   // next head rewrites Gt/Ps
  }

  // ---- epilogue (fp32 out): write (BR=0) or accumulate (BR=1)
  #pragma unroll
  for (int r=0;r<4;r++)
    #pragma unroll
    for (int c=0;c<4;c++)
      #pragma unroll
      for (int g=0; g<4; g++){
        int t   = r*16 + quad*4 + g;
        int col = cw + c*16 + m16;
        int off = tok(t) + col;
        float vv = Z[r][c][g];
        if (BR==1) vv += out[off];
        out[off] = vv;
      }
}

extern "C" void kernel_launch(void* const* d_in, const int* in_sizes, int n_in,
                              void* d_out, int out_size, void* d_ws, size_t ws_size,
                              hipStream_t stream) {
  const float* x = (const float*)d_in[0];
  const float* q = (const float*)d_in[1];
  const float* k = (const float*)d_in[2];
  const float* v = (const float*)d_in[3];
  const float* o = (const float*)d_in[4];
  u16* ws   = (u16*)d_ws;                    // needs ~2.24 MB
  u16* mhi  = ws;                            // 524288
  u16* mlo  = ws + 524288;                   // 524288
  u16* vT   = ws + 1048576;                  // 65536
  float* soP = (float*)(ws + 1114112);       // 2048 floats
  float* out = (float*)d_out;

  mh_kernel<<<2048, 256, 0, stream>>>(q, k, mhi, mlo);
  vt_kernel<<<256, 256, 0, stream>>>(v, vT);
  so_kernel<<<8, 256, 0, stream>>>(o, soP);

  (void)hipFuncSetAttribute(reinterpret_cast<const void*>(&attn_kernel<0>),
                            hipFuncAttributeMaxDynamicSharedMemorySize, SMEM_BYTES);
  (void)hipFuncSetAttribute(reinterpret_cast<const void*>(&attn_kernel<1>),
                            hipFuncAttributeMaxDynamicSharedMemorySize, SMEM_BYTES);
  attn_kernel<0><<<512, 256, SMEM_BYTES, stream>>>(x, mhi, mlo, vT, soP, out);
  attn_kernel<1><<<512, 256, SMEM_BYTES, stream>>>(x, mhi, mlo, vT, soP, out);
}

// Round 4
// 403.984 us; speedup vs baseline: 1.0942x; 1.0942x over previous
//
#include <hip/hip_runtime.h>

typedef unsigned short u16;
typedef __attribute__((ext_vector_type(8))) short short8;
typedef __attribute__((ext_vector_type(4))) float f32x4;

__device__ __forceinline__ float bf2f(u16 u){ return __uint_as_float(((unsigned)u)<<16); }
__device__ __forceinline__ u16 f2bf(float f){
  unsigned u = __float_as_uint(f);
  unsigned r = u + 0x7fffu + ((u>>16)&1u);   // RNE (no NaN/inf in this problem)
  return (u16)(r>>16);
}

#define MFMA16(a,b,c) __builtin_amdgcn_mfma_f32_16x16x32_bf16(a,b,c,0,0,0)

// ---- attn LDS layout (u16 offsets). Strides 264/72: 2-way bank aliasing (free).
static constexpr int XS_STR  = 264;
static constexpr int PS_STR  = 72;
static constexpr int WT_STR  = 72;
static constexpr int XHI_OFF = 0;         // 64x264
static constexpr int XLO_OFF = 16896;
static constexpr int GT_OFF  = 33792;     // 64x264, holds Ghi then Glo per head
static constexpr int XVT_OFF = 50688;     // 256x72, persistent Xv^T
static constexpr int PS_OFF  = 69120;     // 64x72
static constexpr int SMEM_BYTES = 73728*2;   // 147456 B

// ---- mh LDS
static constexpr int MH_SMEM = 70656*2;      // Qhi/Qlo 64x264 + Chi/Clo 256x72

// ---- ws layout (u16): mhi[524288] | mlo[524288] | scratch[131072]
//   scratch holds khi/klo for mh, then (stream-ordered) vT + so reuse it.

__global__ void ksplit_kernel(const float* __restrict__ k,
                              u16* __restrict__ khi, u16* __restrict__ klo){
  int e = blockIdx.x*256 + threadIdx.x;    // 65536
  float f = k[e];
  u16 hi = f2bf(f);
  khi[e] = hi;
  klo[e] = f2bf(f - bf2f(hi));
}

// MhT[h][dp][d] = sum_ko q[h][d][ko]*k[dp][ko], hi/lo bf16 via 3-term MFMA
__global__ __launch_bounds__(256,1) void mh_kernel(
    const float* __restrict__ q, const u16* __restrict__ khi,
    const u16* __restrict__ klo, u16* __restrict__ mhi, u16* __restrict__ mlo)
{
  extern __shared__ u16 sm[];
  u16* Qhi = sm;
  u16* Qlo = sm + 16896;
  u16* Chi = sm + 33792;
  u16* Clo = sm + 52224;

  const int tid = threadIdx.x;
  const int w = tid >> 6, lane = tid & 63;
  const int quad = lane >> 4, m16 = lane & 15;
  const int cw = w << 6, koq = quad << 3;
  const int h = blockIdx.x >> 2, dt = (blockIdx.x & 3) << 6;

  // stage q rows [dt, dt+64) as hi/lo
  #pragma unroll
  for (int i=0;i<16;i++){
    int idx4 = i*256 + tid;
    int tr = idx4 >> 6, c4 = (idx4 & 63) << 2;
    const float4 xv = *(const float4*)(q + (((h<<8)+dt+tr)<<8) + c4);
    ushort4 hv, lv;
    hv.x=f2bf(xv.x); lv.x=f2bf(xv.x-bf2f(hv.x));
    hv.y=f2bf(xv.y); lv.y=f2bf(xv.y-bf2f(hv.y));
    hv.z=f2bf(xv.z); lv.z=f2bf(xv.z-bf2f(hv.z));
    hv.w=f2bf(xv.w); lv.w=f2bf(xv.w-bf2f(hv.w));
    *(ushort4*)&Qhi[tr*XS_STR + c4] = hv;
    *(ushort4*)&Qlo[tr*XS_STR + c4] = lv;
  }
  __syncthreads();

  const f32x4 zf = {0.f,0.f,0.f,0.f};
  f32x4 acc[4][4];
  #pragma unroll
  for (int r=0;r<4;r++)
    #pragma unroll
    for (int c=0;c<4;c++) acc[r][c] = zf;

  short8 Bh[2][4], Bl[2][4];
  #pragma unroll
  for (int c=0;c<4;c++){
    Bh[0][c] = *(const short8*)&khi[(cw + c*16 + m16)*256 + koq];
    Bl[0][c] = *(const short8*)&klo[(cw + c*16 + m16)*256 + koq];
  }
  #pragma unroll
  for (int kk=0;kk<8;kk++){
    const int cur = kk&1, nxt = cur^1;
    if (kk<7){
      const int ko2 = ((kk+1)<<5) + koq;
      #pragma unroll
      for (int c=0;c<4;c++){
        Bh[nxt][c] = *(const short8*)&khi[(cw + c*16 + m16)*256 + ko2];
        Bl[nxt][c] = *(const short8*)&klo[(cw + c*16 + m16)*256 + ko2];
      }
    }
    const int ko = (kk<<5) + koq;
    short8 Ah[4], Al[4];
    #pragma unroll
    for (int r=0;r<4;r++) Ah[r] = *(const short8*)&Qhi[(r*16+m16)*XS_STR + ko];
    #pragma unroll
    for (int r=0;r<4;r++) Al[r] = *(const short8*)&Qlo[(r*16+m16)*XS_STR + ko];
    #pragma unroll
    for (int r=0;r<4;r++)
      #pragma unroll
      for (int c=0;c<4;c++){
        acc[r][c] = MFMA16(Ah[r], Bh[cur][c], acc[r][c]);
        acc[r][c] = MFMA16(Ah[r], Bl[cur][c], acc[r][c]);
        acc[r][c] = MFMA16(Al[r], Bh[cur][c], acc[r][c]);
      }
  }

  // write C hi/lo to LDS as [dp][d]
  #pragma unroll
  for (int r=0;r<4;r++)
    #pragma unroll
    for (int c=0;c<4;c++)
      #pragma unroll
      for (int g=0; g<4; g++){
        int drow = r*16 + quad*4 + g;
        int dp   = cw + c*16 + m16;
        float vv = acc[r][c][g];
        u16 hh = f2bf(vv);
        Chi[dp*WT_STR + drow] = hh;
        Clo[dp*WT_STR + drow] = f2bf(vv - bf2f(hh));
      }
  __syncthreads();

  // coalesced 16B stores: mh[(h*256+dp)*256 + dt + i]
  #pragma unroll
  for (int p=0;p<8;p++){
    int ch = tid + (p<<8);
    int dp = ch >> 3, i8 = (ch & 7) << 3;
    *(int4*)&mhi[(((h<<8)+dp)<<8) + dt + i8] = *(const int4*)&Chi[dp*WT_STR + i8];
    *(int4*)&mlo[(((h<<8)+dp)<<8) + dt + i8] = *(const int4*)&Clo[dp*WT_STR + i8];
  }
}

// vT[vout][d] = bf16(v[d][vout]) via LDS-tiled transpose
__global__ void vt_kernel(const float* __restrict__ v, u16* __restrict__ vT){
  __shared__ float Ts[64*65];
  const int tid = threadIdx.x;
  const int bi = (blockIdx.x>>2)<<6, bj = (blockIdx.x&3)<<6;
  #pragma unroll
  for (int p=0;p<4;p++){
    int idx4 = tid + (p<<8);
    int i = idx4 >> 4, c4 = (idx4 & 15) << 2;
    const float4 f4 = *(const float4*)(v + ((bi+i)<<8) + bj + c4);
    Ts[i*65+c4] = f4.x; Ts[i*65+c4+1] = f4.y; Ts[i*65+c4+2] = f4.z; Ts[i*65+c4+3] = f4.w;
  }
  __syncthreads();
  #pragma unroll
  for (int p=0;p<2;p++){
    int ch = tid + (p<<8);
    int j = ch >> 3, i8 = (ch & 7) << 3;
    short8 t8;
    #pragma unroll
    for (int e=0;e<8;e++) t8[e] = (short)f2bf(Ts[(i8+e)*65 + j]);
    *(short8*)&vT[((bj+j)<<8) + bi + i8] = t8;
  }
}

// so[h][d] = sum_v o[h][d][v]  (fp32, coalesced wave-reduce)
__global__ void so_kernel(const float* __restrict__ o, float* __restrict__ so){
  int h = blockIdx.x;
  int w = threadIdx.x >> 6, l = threadIdx.x & 63;
  for (int i=0;i<64;i++){
    int row = w*64 + i;
    const float4 f4 = *(const float4*)(o + (((h<<8)+row)<<8) + (l<<2));
    float s = f4.x + f4.y + f4.z + f4.w;
    #pragma unroll
    for (int off=32; off>=1; off>>=1) s += __shfl_xor(s, off, 64);
    if (l==0) so[(h<<8)+row] = s;
  }
}

// BR=0: per-(b,y) attention over m, heads 0..3, writes out.
// BR=1: per-(b,x) attention over n, heads 4..7, accumulates into out.
template<int BR>
__global__ __launch_bounds__(256,1) void attn_kernel(
    const float* __restrict__ x, const u16* __restrict__ mhiP,
    const u16* __restrict__ mloP, const u16* __restrict__ vT,
    const float* __restrict__ soP, float* __restrict__ out)
{
  extern __shared__ u16 sm[];
  u16* Xhi = sm + XHI_OFF;
  u16* Xlo = sm + XLO_OFF;
  u16* Gt  = sm + GT_OFF;
  u16* Xvt = sm + XVT_OFF;
  u16* Ps  = sm + PS_OFF;

  const int tid  = threadIdx.x;
  const int w    = tid >> 6, lane = tid & 63;
  const int quad = lane >> 4, m16 = lane & 15;
  const int b    = blockIdx.x >> 6, s = blockIdx.x & 63;
  const int cw   = w << 6;
  const int koq  = quad << 3;

  auto tok = [&](int t)->int {
    int m = (BR==0) ? t : s;
    int n = (BR==0) ? s : t;
    return (((b<<6) + m) << 14) + (n << 8);
  };

  // ---- stage X hi/lo
  #pragma unroll
  for (int i=0;i<16;i++){
    int idx4 = i*256 + tid;
    int tr = idx4 >> 6, c4 = (idx4 & 63) << 2;
    const float4 xv = *(const float4*)(x + tok(tr) + c4);
    ushort4 hv, lv;
    hv.x=f2bf(xv.x); lv.x=f2bf(xv.x-bf2f(hv.x));
    hv.y=f2bf(xv.y); lv.y=f2bf(xv.y-bf2f(hv.y));
    hv.z=f2bf(xv.z); lv.z=f2bf(xv.z-bf2f(hv.z));
    hv.w=f2bf(xv.w); lv.w=f2bf(xv.w-bf2f(hv.w));
    *(ushort4*)&Xhi[tr*XS_STR + c4] = hv;
    *(ushort4*)&Xlo[tr*XS_STR + c4] = lv;
  }
  __syncthreads();

  const f32x4 zf = {0.f,0.f,0.f,0.f};
  f32x4 acc[4][4];

  // acc = Xhi@Whi + Xhi@Wlo + Xlo@Whi, B from global, double-buffered
  auto mm3 = [&](const u16* __restrict__ Whi, const u16* __restrict__ Wlo){
    #pragma unroll
    for (int r=0;r<4;r++)
      #pragma unroll
      for (int c=0;c<4;c++) acc[r][c] = zf;
    short8 Bh[2][4], Bl[2][4];
    #pragma unroll
    for (int c=0;c<4;c++){
      Bh[0][c] = *(const short8*)&Whi[(cw + c*16 + m16)*256 + koq];
      Bl[0][c] = *(const short8*)&Wlo[(cw + c*16 + m16)*256 + koq];
    }
    #pragma unroll
    for (int kk=0;kk<8;kk++){
      const int cur = kk&1, nxt = cur^1;
      if (kk<7){
        const int ko2 = ((kk+1)<<5) + koq;
        #pragma unroll
        for (int c=0;c<4;c++){
          Bh[nxt][c] = *(const short8*)&Whi[(cw + c*16 + m16)*256 + ko2];
          Bl[nxt][c] = *(const short8*)&Wlo[(cw + c*16 + m16)*256 + ko2];
        }
      }
      const int ko = (kk<<5) + koq;
      short8 Ah[4], Al[4];
      #pragma unroll
      for (int r=0;r<4;r++) Ah[r] = *(const short8*)&Xhi[(r*16+m16)*XS_STR + ko];
      #pragma unroll
      for (int r=0;r<4;r++) Al[r] = *(const short8*)&Xlo[(r*16+m16)*XS_STR + ko];
      #pragma unroll
      for (int r=0;r<4;r++)
        #pragma unroll
        for (int c=0;c<4;c++){
          acc[r][c] = MFMA16(Ah[r], Bh[cur][c], acc[r][c]);
          acc[r][c] = MFMA16(Ah[r], Bl[cur][c], acc[r][c]);
          acc[r][c] = MFMA16(Al[r], Bh[cur][c], acc[r][c]);
        }
    }
  };

  // ---- Xv = Xhi @ vT (once), store unscaled Xv^T in LDS
  {
    #pragma unroll
    for (int r=0;r<4;r++)
      #pragma unroll
      for (int c=0;c<4;c++) acc[r][c] = zf;
    #pragma unroll
    for (int kk=0;kk<8;kk++){
      const int ko = (kk<<5) + koq;
      short8 A[4], Bf[4];
      #pragma unroll
      for (int r=0;r<4;r++) A[r]  = *(const short8*)&Xhi[(r*16+m16)*XS_STR + ko];
      #pragma unroll
      for (int c=0;c<4;c++) Bf[c] = *(const short8*)&vT[(cw + c*16 + m16)*256 + ko];
      #pragma unroll
      for (int r=0;r<4;r++)
        #pragma unroll
        for (int c=0;c<4;c++) acc[r][c] = MFMA16(A[r], Bf[c], acc[r][c]);
    }
    #pragma unroll
    for (int r=0;r<4;r++)
      #pragma unroll
      for (int c=0;c<4;c++)
        #pragma unroll
        for (int g=0; g<4; g++){
          int z  = r*16 + quad*4 + g;
          int vc = cw + c*16 + m16;
          Xvt[vc*WT_STR + z] = f2bf(acc[r][c][g]);
        }
    // visibility of Xvt to other waves is guaranteed by the first in-loop barrier
  }

  f32x4 Z[4][4];
  #pragma unroll
  for (int r=0;r<4;r++)
    #pragma unroll
    for (int c=0;c<4;c++) Z[r][c] = zf;

  for (int h=0; h<4; h++){
    const int gh = BR*4 + h;

    // ---- G = X @ Mh[gh] (3-term hi/lo); write Ghi
    mm3(mhiP + gh*65536, mloP + gh*65536);
    #pragma unroll
    for (int r=0;r<4;r++)
      #pragma unroll
      for (int c=0;c<4;c++)
        #pragma unroll
        for (int g=0; g<4; g++){
          int row = r*16 + quad*4 + g;
          int col = cw + c*16 + m16;
          Gt[row*XS_STR + col] = f2bf(acc[r][c][g]);
        }
    __syncthreads();                       // bar1: Ghi (+Xvt on h==0) visible

    // ---- logits A: Ghi@Xhi^T + Ghi@Xlo^T
    f32x4 L[4];
    #pragma unroll
    for (int c=0;c<4;c++) L[c] = zf;
    #pragma unroll
    for (int kk=0;kk<8;kk++){
      const int ko = (kk<<5) + koq;
      short8 A = *(const short8*)&Gt[(w*16+m16)*XS_STR + ko];
      #pragma unroll
      for (int c=0;c<4;c++)
        L[c] = MFMA16(A, *(const short8*)&Xhi[(c*16+m16)*XS_STR + ko], L[c]);
      #pragma unroll
      for (int c=0;c<4;c++)
        L[c] = MFMA16(A, *(const short8*)&Xlo[(c*16+m16)*XS_STR + ko], L[c]);
    }
    __syncthreads();                       // bar2: Gt reads done -> overwrite
    #pragma unroll
    for (int r=0;r<4;r++)
      #pragma unroll
      for (int c=0;c<4;c++)
        #pragma unroll
        for (int g=0; g<4; g++){
          int row = r*16 + quad*4 + g;
          int col = cw + c*16 + m16;
          float vv = acc[r][c][g];
          u16 hh = f2bf(vv);
          Gt[row*XS_STR + col] = f2bf(vv - bf2f(hh));   // Glo
        }
    __syncthreads();                       // bar3: Glo visible

    // ---- logits B: Glo@Xhi^T
    #pragma unroll
    for (int kk=0;kk<8;kk++){
      const int ko = (kk<<5) + koq;
      short8 A = *(const short8*)&Gt[(w*16+m16)*XS_STR + ko];
      #pragma unroll
      for (int c=0;c<4;c++)
        L[c] = MFMA16(A, *(const short8*)&Xhi[(c*16+m16)*XS_STR + ko], L[c]);
    }

    // ---- softmax (row = w*16+quad*4+g; 64 z-values in quad lanes x 4 c-tiles)
    #pragma unroll
    for (int g=0; g<4; g++){
      float mx = fmaxf(fmaxf(L[0][g],L[1][g]), fmaxf(L[2][g],L[3][g]));
      #pragma unroll
      for (int off=1; off<16; off<<=1) mx = fmaxf(mx, __shfl_xor(mx, off, 64));
      float sum = 0.f;
      #pragma unroll
      for (int c=0;c<4;c++){ float e = __expf(L[c][g]-mx); L[c][g] = e; sum += e; }
      #pragma unroll
      for (int off=1; off<16; off<<=1) sum += __shfl_xor(sum, off, 64);
      float inv = 1.f / sum;
      int row = w*16 + quad*4 + g;
      #pragma unroll
      for (int c=0;c<4;c++) Ps[row*PS_STR + c*16 + m16] = f2bf(L[c][g]*inv);
    }
    __syncthreads();                       // bar4: Ps visible

    // ---- Y = P @ Xv (reuse acc), then Z += so * Y (fp32)
    #pragma unroll
    for (int r=0;r<4;r++)
      #pragma unroll
      for (int c=0;c<4;c++) acc[r][c] = zf;
    #pragma unroll
    for (int kk=0;kk<2;kk++){
      const int ko = (kk<<5) + koq;
      short8 A[4], Bf[4];
      #pragma unroll
      for (int r=0;r<4;r++) A[r]  = *(const short8*)&Ps[(r*16+m16)*PS_STR + ko];
      #pragma unroll
      for (int c=0;c<4;c++) Bf[c] = *(const short8*)&Xvt[(cw + c*16 + m16)*WT_STR + ko];
      #pragma unroll
      for (int r=0;r<4;r++)
        #pragma unroll
        for (int c=0;c<4;c++) acc[r][c] = MFMA16(A[r], Bf[c], acc[r][c]);
    }
    float sc[4];
    #pragma unroll
    for (int c=0;c<4;c++) sc[c] = soP[gh*256 + cw + c*16 + m16];
    #pragma unroll
    for (int r=0;r<4;r++)
      #pragma unroll
      for (int c=0;c<4;c++)
        #pragma unroll
        for (int g=0; g<4; g++) Z[r][c][g] += sc[c]*acc[r][c][g];
    // no loop-end barrier needed: next writes (Gt) are disjoint from Ps/Xvt reads,
    // and bar1 collectively fences before next logits reads.
  }

  // ---- epilogue (fp32): write (BR=0) or accumulate (BR=1)
  #pragma unroll
  for (int r=0;r<4;r++)
    #pragma unroll
    for (int c=0;c<4;c++)
      #pragma unroll
      for (int g=0; g<4; g++){
        int t   = r*16 + quad*4 + g;
        int col = cw + c*16 + m16;
        int off = tok(t) + col;
        float vv = Z[r][c][g];
        if (BR==1) vv += out[off];
        out[off] = vv;
      }
}

extern "C" void kernel_launch(void* const* d_in, const int* in_sizes, int n_in,
                              void* d_out, int out_size, void* d_ws, size_t ws_size,
                              hipStream_t stream) {
  const float* x = (const float*)d_in[0];
  const float* q = (const float*)d_in[1];
  const float* k = (const float*)d_in[2];
  const float* v = (const float*)d_in[3];
  const float* o = (const float*)d_in[4];
  u16* ws   = (u16*)d_ws;                    // needs ~2.3 MB
  u16* mhi  = ws;                            // 524288
  u16* mlo  = ws + 524288;                   // 524288
  u16* scr  = ws + 1048576;                  // 131072 scratch (aliased by order)
  u16* khi  = scr;                           // used by mh only
  u16* klo  = scr + 65536;
  u16* vT   = scr;                           // written after mh completes
  float* soP = (float*)(scr + 65536);
  float* out = (float*)d_out;

  ksplit_kernel<<<256, 256, 0, stream>>>(k, khi, klo);
  (void)hipFuncSetAttribute(reinterpret_cast<const void*>(&mh_kernel),
                            hipFuncAttributeMaxDynamicSharedMemorySize, MH_SMEM);
  mh_kernel<<<32, 256, MH_SMEM, stream>>>(q, khi, klo, mhi, mlo);
  vt_kernel<<<16, 256, 0, stream>>>(v, vT);       // overwrites khi region (ordered)
  so_kernel<<<8, 256, 0, stream>>>(o, soP);       // overwrites klo region (ordered)

  (void)hipFuncSetAttribute(reinterpret_cast<const void*>(&attn_kernel<0>),
                            hipFuncAttributeMaxDynamicSharedMemorySize, SMEM_BYTES);
  (void)hipFuncSetAttribute(reinterpret_cast<const void*>(&attn_kernel<1>),
                            hipFuncAttributeMaxDynamicSharedMemorySize, SMEM_BYTES);
  attn_kernel<0><<<512, 256, SMEM_BYTES, stream>>>(x, mhi, mlo, vT, soP, out);
  attn_kernel<1><<<512, 256, SMEM_BYTES, stream>>>(x, mhi, mlo, vT, soP, out);
}

// Round 5
// 355.139 us; speedup vs baseline: 1.2447x; 1.1375x over previous
//
#include <hip/hip_runtime.h>

typedef unsigned short u16;
typedef __attribute__((ext_vector_type(8))) short short8;
typedef __attribute__((ext_vector_type(4))) float f32x4;

__device__ __forceinline__ float bf2f(u16 u){ return __uint_as_float(((unsigned)u)<<16); }
__device__ __forceinline__ u16 f2bf(float f){
  unsigned u = __float_as_uint(f);
  unsigned r = u + 0x7fffu + ((u>>16)&1u);   // RNE (no NaN/inf in this problem)
  return (u16)(r>>16);
}

#define MFMA16(a,b,c) __builtin_amdgcn_mfma_f32_16x16x32_bf16(a,b,c,0,0,0)

// ---- attn LDS layout (u16 offsets). Strides 264/72: 2-way bank aliasing (free).
static constexpr int XS_STR  = 264;
static constexpr int PS_STR  = 72;
static constexpr int WT_STR  = 72;
static constexpr int XHI_OFF = 0;         // 64x264
static constexpr int XLO_OFF = 16896;
static constexpr int GT_OFF  = 33792;     // 64x264, Ghi then Glo per head
static constexpr int XVT_OFF = 50688;     // 256x72, persistent Xv^T
static constexpr int PS_OFF  = 69120;     // 64x72
static constexpr int SMRE_OFF= 73728;     // 64 rows x 2 halves x (mx,sum) f32 = 512 u16
static constexpr int SMEM_BYTES = (73728 + 512)*2;   // 148480 B

// ---- mh LDS
static constexpr int MH_SMEM = 70656*2;   // Qhi/Qlo 64x264 + Chi/Clo 256x72

// ---- ws layout (u16): mhi[524288] | mlo[524288] | khi[65536] | klo[65536]
//                       | vT[65536] | soP[4096 u16 = 2048 f32]   (~2.38 MB)

// prep: blocks 0..63 = k hi/lo split, 64..79 = v transpose, 80..335 = so row-sums
__global__ void prep_kernel(const float* __restrict__ k, const float* __restrict__ v,
                            const float* __restrict__ o, u16* __restrict__ khi,
                            u16* __restrict__ klo, u16* __restrict__ vT,
                            float* __restrict__ soP){
  __shared__ float Ts[64*65];
  const int blk = blockIdx.x, tid = threadIdx.x;
  if (blk < 64){
    int base = blk*1024 + tid*4;
    const float4 f4 = *(const float4*)(k + base);
    ushort4 hv, lv;
    hv.x=f2bf(f4.x); lv.x=f2bf(f4.x-bf2f(hv.x));
    hv.y=f2bf(f4.y); lv.y=f2bf(f4.y-bf2f(hv.y));
    hv.z=f2bf(f4.z); lv.z=f2bf(f4.z-bf2f(hv.z));
    hv.w=f2bf(f4.w); lv.w=f2bf(f4.w-bf2f(hv.w));
    *(ushort4*)&khi[base] = hv;
    *(ushort4*)&klo[base] = lv;
  } else if (blk < 80){
    int t = blk - 64;
    const int bi = (t>>2)<<6, bj = (t&3)<<6;
    #pragma unroll
    for (int p=0;p<4;p++){
      int idx4 = tid + (p<<8);
      int i = idx4 >> 4, c4 = (idx4 & 15) << 2;
      const float4 f4 = *(const float4*)(v + ((bi+i)<<8) + bj + c4);
      Ts[i*65+c4]=f4.x; Ts[i*65+c4+1]=f4.y; Ts[i*65+c4+2]=f4.z; Ts[i*65+c4+3]=f4.w;
    }
    __syncthreads();
    #pragma unroll
    for (int p=0;p<2;p++){
      int ch = tid + (p<<8);
      int j = ch >> 3, i8 = (ch & 7) << 3;
      short8 t8;
      #pragma unroll
      for (int e=0;e<8;e++) t8[e] = (short)f2bf(Ts[(i8+e)*65 + j]);
      *(short8*)&vT[((bj+j)<<8) + bi + i8] = t8;
    }
  } else {
    int p = blk - 80;                      // 256 blocks: 8 h x 32 chunks of 8 rows
    int h = p >> 5, base = (p & 31) << 3;
    int w = tid >> 6, l = tid & 63;
    #pragma unroll
    for (int i=0;i<2;i++){
      int row = base + w*2 + i;
      const float4 f4 = *(const float4*)(o + (((h<<8)+row)<<8) + (l<<2));
      float s = f4.x + f4.y + f4.z + f4.w;
      #pragma unroll
      for (int off=32; off>=1; off>>=1) s += __shfl_xor(s, off, 64);
      if (l==0) soP[(h<<8)+row] = s;
    }
  }
}

// MhT[h][dp][d] = sum_ko q[h][d][ko]*k[dp][ko], hi/lo bf16 via 3-term MFMA
__global__ __launch_bounds__(256,1) void mh_kernel(
    const float* __restrict__ q, const u16* __restrict__ khi,
    const u16* __restrict__ klo, u16* __restrict__ mhi, u16* __restrict__ mlo)
{
  extern __shared__ u16 sm[];
  u16* Qhi = sm;
  u16* Qlo = sm + 16896;
  u16* Chi = sm + 33792;
  u16* Clo = sm + 52224;

  const int tid = threadIdx.x;
  const int w = tid >> 6, lane = tid & 63;
  const int quad = lane >> 4, m16 = lane & 15;
  const int cw = w << 6, koq = quad << 3;
  const int h = blockIdx.x >> 2, dt = (blockIdx.x & 3) << 6;

  #pragma unroll
  for (int i=0;i<16;i++){
    int idx4 = i*256 + tid;
    int tr = idx4 >> 6, c4 = (idx4 & 63) << 2;
    const float4 xv = *(const float4*)(q + (((h<<8)+dt+tr)<<8) + c4);
    ushort4 hv, lv;
    hv.x=f2bf(xv.x); lv.x=f2bf(xv.x-bf2f(hv.x));
    hv.y=f2bf(xv.y); lv.y=f2bf(xv.y-bf2f(hv.y));
    hv.z=f2bf(xv.z); lv.z=f2bf(xv.z-bf2f(hv.z));
    hv.w=f2bf(xv.w); lv.w=f2bf(xv.w-bf2f(hv.w));
    *(ushort4*)&Qhi[tr*XS_STR + c4] = hv;
    *(ushort4*)&Qlo[tr*XS_STR + c4] = lv;
  }
  __syncthreads();

  const f32x4 zf = {0.f,0.f,0.f,0.f};
  f32x4 acc[4][4];
  #pragma unroll
  for (int r=0;r<4;r++)
    #pragma unroll
    for (int c=0;c<4;c++) acc[r][c] = zf;

  short8 Bh[2][4], Bl[2][4];
  #pragma unroll
  for (int c=0;c<4;c++){
    Bh[0][c] = *(const short8*)&khi[(cw + c*16 + m16)*256 + koq];
    Bl[0][c] = *(const short8*)&klo[(cw + c*16 + m16)*256 + koq];
  }
  #pragma unroll
  for (int kk=0;kk<8;kk++){
    const int cur = kk&1, nxt = cur^1;
    if (kk<7){
      const int ko2 = ((kk+1)<<5) + koq;
      #pragma unroll
      for (int c=0;c<4;c++){
        Bh[nxt][c] = *(const short8*)&khi[(cw + c*16 + m16)*256 + ko2];
        Bl[nxt][c] = *(const short8*)&klo[(cw + c*16 + m16)*256 + ko2];
      }
    }
    const int ko = (kk<<5) + koq;
    short8 Ah[4], Al[4];
    #pragma unroll
    for (int r=0;r<4;r++) Ah[r] = *(const short8*)&Qhi[(r*16+m16)*XS_STR + ko];
    #pragma unroll
    for (int r=0;r<4;r++) Al[r] = *(const short8*)&Qlo[(r*16+m16)*XS_STR + ko];
    #pragma unroll
    for (int r=0;r<4;r++)
      #pragma unroll
      for (int c=0;c<4;c++){
        acc[r][c] = MFMA16(Ah[r], Bh[cur][c], acc[r][c]);
        acc[r][c] = MFMA16(Ah[r], Bl[cur][c], acc[r][c]);
        acc[r][c] = MFMA16(Al[r], Bh[cur][c], acc[r][c]);
      }
  }

  #pragma unroll
  for (int r=0;r<4;r++)
    #pragma unroll
    for (int c=0;c<4;c++)
      #pragma unroll
      for (int g=0; g<4; g++){
        int drow = r*16 + quad*4 + g;
        int dp   = cw + c*16 + m16;
        float vv = acc[r][c][g];
        u16 hh = f2bf(vv);
        Chi[dp*WT_STR + drow] = hh;
        Clo[dp*WT_STR + drow] = f2bf(vv - bf2f(hh));
      }
  __syncthreads();

  #pragma unroll
  for (int p=0;p<8;p++){
    int ch = tid + (p<<8);
    int dp = ch >> 3, i8 = (ch & 7) << 3;
    *(int4*)&mhi[(((h<<8)+dp)<<8) + dt + i8] = *(const int4*)&Chi[dp*WT_STR + i8];
    *(int4*)&mlo[(((h<<8)+dp)<<8) + dt + i8] = *(const int4*)&Clo[dp*WT_STR + i8];
  }
}

// Merged attention: blocks [0,512) = branch 0 (per-(b,y), heads 0..3),
// blocks [512,1024) = branch 1 (per-(b,x), heads 4..7). out pre-zeroed; atomicAdd.
// 512 threads = 8 waves -> 2 waves/SIMD at 1 block/CU (148 KB LDS).
__global__ __launch_bounds__(512,2) void attn_kernel(
    const float* __restrict__ x, const u16* __restrict__ mhiP,
    const u16* __restrict__ mloP, const u16* __restrict__ vT,
    const float* __restrict__ soP, float* __restrict__ out)
{
  extern __shared__ u16 sm[];
  u16* Xhi = sm + XHI_OFF;
  u16* Xlo = sm + XLO_OFF;
  u16* Gt  = sm + GT_OFF;
  u16* Xvt = sm + XVT_OFF;
  u16* Ps  = sm + PS_OFF;
  float* SMf = (float*)(sm + SMRE_OFF);   // [row][half][mx,sum]

  const int tid  = threadIdx.x;
  const int w    = tid >> 6, lane = tid & 63;
  const int quad = lane >> 4, m16 = lane & 15;
  const int br   = blockIdx.x >> 9;
  const int idx  = blockIdx.x & 511;
  const int b    = idx >> 6, s = idx & 63;
  const int cw   = w << 5;            // 32-col strip for mm3/Xv/Y
  const int rs   = (w >> 1) << 4;     // logits: 16-row strip
  const int zh   = w & 1;             // logits: z half (32 cols)
  const int koq  = quad << 3;

  auto tok = [&](int t)->int {
    int m = br ? s : t;
    int n = br ? t : s;
    return (((b<<6) + m) << 14) + (n << 8);
  };

  // ---- stage X hi/lo (4096 float4, 8 iters x 512 threads)
  #pragma unroll
  for (int i=0;i<8;i++){
    int idx4 = i*512 + tid;
    int tr = idx4 >> 6, c4 = (idx4 & 63) << 2;
    const float4 xv = *(const float4*)(x + tok(tr) + c4);
    ushort4 hv, lv;
    hv.x=f2bf(xv.x); lv.x=f2bf(xv.x-bf2f(hv.x));
    hv.y=f2bf(xv.y); lv.y=f2bf(xv.y-bf2f(hv.y));
    hv.z=f2bf(xv.z); lv.z=f2bf(xv.z-bf2f(hv.z));
    hv.w=f2bf(xv.w); lv.w=f2bf(xv.w-bf2f(hv.w));
    *(ushort4*)&Xhi[tr*XS_STR + c4] = hv;
    *(ushort4*)&Xlo[tr*XS_STR + c4] = lv;
  }
  __syncthreads();

  const f32x4 zf = {0.f,0.f,0.f,0.f};
  f32x4 acc[4][2];

  // acc = Xhi@Whi + Xhi@Wlo + Xlo@Whi over wave's 32-col strip, dbuf B-loads
  auto mm3 = [&](const u16* __restrict__ Whi, const u16* __restrict__ Wlo){
    #pragma unroll
    for (int r=0;r<4;r++){ acc[r][0] = zf; acc[r][1] = zf; }
    short8 Bh[2][2], Bl[2][2];
    #pragma unroll
    for (int c=0;c<2;c++){
      Bh[0][c] = *(const short8*)&Whi[(cw + c*16 + m16)*256 + koq];
      Bl[0][c] = *(const short8*)&Wlo[(cw + c*16 + m16)*256 + koq];
    }
    #pragma unroll
    for (int kk=0;kk<8;kk++){
      const int cur = kk&1, nxt = cur^1;
      if (kk<7){
        const int ko2 = ((kk+1)<<5) + koq;
        #pragma unroll
        for (int c=0;c<2;c++){
          Bh[nxt][c] = *(const short8*)&Whi[(cw + c*16 + m16)*256 + ko2];
          Bl[nxt][c] = *(const short8*)&Wlo[(cw + c*16 + m16)*256 + ko2];
        }
      }
      const int ko = (kk<<5) + koq;
      short8 Ah[4], Al[4];
      #pragma unroll
      for (int r=0;r<4;r++) Ah[r] = *(const short8*)&Xhi[(r*16+m16)*XS_STR + ko];
      #pragma unroll
      for (int r=0;r<4;r++) Al[r] = *(const short8*)&Xlo[(r*16+m16)*XS_STR + ko];
      #pragma unroll
      for (int r=0;r<4;r++)
        #pragma unroll
        for (int c=0;c<2;c++){
          acc[r][c] = MFMA16(Ah[r], Bh[cur][c], acc[r][c]);
          acc[r][c] = MFMA16(Ah[r], Bl[cur][c], acc[r][c]);
          acc[r][c] = MFMA16(Al[r], Bh[cur][c], acc[r][c]);
        }
    }
  };

  // ---- Xv = Xhi @ vT over wave's 32 cols; store Xv^T (unscaled) in LDS
  {
    #pragma unroll
    for (int r=0;r<4;r++){ acc[r][0] = zf; acc[r][1] = zf; }
    #pragma unroll
    for (int kk=0;kk<8;kk++){
      const int ko = (kk<<5) + koq;
      short8 A[4], Bf[2];
      #pragma unroll
      for (int r=0;r<4;r++) A[r]  = *(const short8*)&Xhi[(r*16+m16)*XS_STR + ko];
      #pragma unroll
      for (int c=0;c<2;c++) Bf[c] = *(const short8*)&vT[(cw + c*16 + m16)*256 + ko];
      #pragma unroll
      for (int r=0;r<4;r++)
        #pragma unroll
        for (int c=0;c<2;c++) acc[r][c] = MFMA16(A[r], Bf[c], acc[r][c]);
    }
    #pragma unroll
    for (int r=0;r<4;r++)
      #pragma unroll
      for (int c=0;c<2;c++)
        #pragma unroll
        for (int g=0; g<4; g++){
          int z  = r*16 + quad*4 + g;
          int vc = cw + c*16 + m16;
          Xvt[vc*WT_STR + z] = f2bf(acc[r][c][g]);
        }
    // visible after bar1 of head 0
  }

  f32x4 Z[4][2];
  #pragma unroll
  for (int r=0;r<4;r++){ Z[r][0] = zf; Z[r][1] = zf; }

  for (int h=0; h<4; h++){
    const int gh = br*4 + h;

    // ---- G = X @ Mh[gh] (3-term hi/lo); write Ghi (all rows x own 32 cols)
    mm3(mhiP + gh*65536, mloP + gh*65536);
    #pragma unroll
    for (int r=0;r<4;r++)
      #pragma unroll
      for (int c=0;c<2;c++)
        #pragma unroll
        for (int g=0; g<4; g++){
          int row = r*16 + quad*4 + g;
          int col = cw + c*16 + m16;
          Gt[row*XS_STR + col] = f2bf(acc[r][c][g]);
        }
    __syncthreads();                       // bar1: Ghi (+Xvt at h==0) visible

    // ---- logits A: Ghi@Xhi^T + Ghi@Xlo^T. Wave: rows rs..rs+16, z in [zh*32,+32)
    f32x4 L[2];
    L[0] = zf; L[1] = zf;
    #pragma unroll
    for (int kk=0;kk<8;kk++){
      const int ko = (kk<<5) + koq;
      short8 A = *(const short8*)&Gt[(rs+m16)*XS_STR + ko];
      #pragma unroll
      for (int c=0;c<2;c++)
        L[c] = MFMA16(A, *(const short8*)&Xhi[((zh<<5) + c*16+m16)*XS_STR + ko], L[c]);
      #pragma unroll
      for (int c=0;c<2;c++)
        L[c] = MFMA16(A, *(const short8*)&Xlo[((zh<<5) + c*16+m16)*XS_STR + ko], L[c]);
    }
    __syncthreads();                       // bar2: Gt-hi reads done -> overwrite
    #pragma unroll
    for (int r=0;r<4;r++)
      #pragma unroll
      for (int c=0;c<2;c++)
        #pragma unroll
        for (int g=0; g<4; g++){
          int row = r*16 + quad*4 + g;
          int col = cw + c*16 + m16;
          float vv = acc[r][c][g];
          u16 hh = f2bf(vv);
          Gt[row*XS_STR + col] = f2bf(vv - bf2f(hh));   // Glo
        }
    __syncthreads();                       // bar3: Glo visible

    // ---- logits B: Glo@Xhi^T
    #pragma unroll
    for (int kk=0;kk<8;kk++){
      const int ko = (kk<<5) + koq;
      short8 A = *(const short8*)&Gt[(rs+m16)*XS_STR + ko];
      #pragma unroll
      for (int c=0;c<2;c++)
        L[c] = MFMA16(A, *(const short8*)&Xhi[((zh<<5) + c*16+m16)*XS_STR + ko], L[c]);
    }

    // ---- softmax: local (32-z half) max/sum, then cross-wave merge via SMf
    float mxl[4], sml[4];
    #pragma unroll
    for (int g=0; g<4; g++){
      float mx = fmaxf(L[0][g], L[1][g]);
      #pragma unroll
      for (int off=1; off<16; off<<=1) mx = fmaxf(mx, __shfl_xor(mx, off, 64));
      float sum = 0.f;
      #pragma unroll
      for (int c=0;c<2;c++){ float e = __expf(L[c][g]-mx); L[c][g] = e; sum += e; }
      #pragma unroll
      for (int off=1; off<16; off<<=1) sum += __shfl_xor(sum, off, 64);
      mxl[g] = mx; sml[g] = sum;
      if (m16 == 0){
        int row = rs + quad*4 + g;
        SMf[row*4 + zh*2]     = mx;
        SMf[row*4 + zh*2 + 1] = sum;
      }
    }
    __syncthreads();                       // bar4: SMf visible
    #pragma unroll
    for (int g=0; g<4; g++){
      int row = rs + quad*4 + g;
      float mxo = SMf[row*4 + (zh^1)*2];
      float smo = SMf[row*4 + (zh^1)*2 + 1];
      float M   = fmaxf(mxl[g], mxo);
      float al  = __expf(mxl[g]-M), ao = __expf(mxo-M);
      float scale = al / (sml[g]*al + smo*ao);
      #pragma unroll
      for (int c=0;c<2;c++)
        Ps[row*PS_STR + (zh<<5) + c*16 + m16] = f2bf(L[c][g]*scale);
    }
    __syncthreads();                       // bar5: Ps visible

    // ---- Y = P @ Xv over wave's 32 cols; Z += so * Y
    #pragma unroll
    for (int r=0;r<4;r++){ acc[r][0] = zf; acc[r][1] = zf; }
    #pragma unroll
    for (int kk=0;kk<2;kk++){
      const int ko = (kk<<5) + koq;
      short8 A[4], Bf[2];
      #pragma unroll
      for (int r=0;r<4;r++) A[r]  = *(const short8*)&Ps[(r*16+m16)*PS_STR + ko];
      #pragma unroll
      for (int c=0;c<2;c++) Bf[c] = *(const short8*)&Xvt[(cw + c*16 + m16)*WT_STR + ko];
      #pragma unroll
      for (int r=0;r<4;r++)
        #pragma unroll
        for (int c=0;c<2;c++) acc[r][c] = MFMA16(A[r], Bf[c], acc[r][c]);
    }
    float sc[2];
    sc[0] = soP[gh*256 + cw + m16];
    sc[1] = soP[gh*256 + cw + 16 + m16];
    #pragma unroll
    for (int r=0;r<4;r++)
      #pragma unroll
      for (int c=0;c<2;c++)
        #pragma unroll
        for (int g=0; g<4; g++) Z[r][c][g] += sc[c]*acc[r][c][g];
    // no trailing barrier: next head's Gt writes precede bar1, and Ps/SMf
    // rewrites happen only after that head's bar4 — all reads here are fenced.
  }

  // ---- epilogue: atomic accumulate into pre-zeroed out
  #pragma unroll
  for (int r=0;r<4;r++)
    #pragma unroll
    for (int c=0;c<2;c++)
      #pragma unroll
      for (int g=0; g<4; g++){
        int t   = r*16 + quad*4 + g;
        int col = cw + c*16 + m16;
        atomicAdd(&out[tok(t) + col], Z[r][c][g]);
      }
}

extern "C" void kernel_launch(void* const* d_in, const int* in_sizes, int n_in,
                              void* d_out, int out_size, void* d_ws, size_t ws_size,
                              hipStream_t stream) {
  const float* x = (const float*)d_in[0];
  const float* q = (const float*)d_in[1];
  const float* k = (const float*)d_in[2];
  const float* v = (const float*)d_in[3];
  const float* o = (const float*)d_in[4];
  u16* ws   = (u16*)d_ws;                    // ~2.38 MB
  u16* mhi  = ws;
  u16* mlo  = ws + 524288;
  u16* khi  = ws + 1048576;
  u16* klo  = ws + 1114112;
  u16* vT   = ws + 1179648;
  float* soP = (float*)(ws + 1245184);
  float* out = (float*)d_out;

  (void)hipMemsetAsync(d_out, 0, (size_t)out_size*sizeof(float), stream);
  prep_kernel<<<336, 256, 0, stream>>>(k, v, o, khi, klo, vT, soP);
  (void)hipFuncSetAttribute(reinterpret_cast<const void*>(&mh_kernel),
                            hipFuncAttributeMaxDynamicSharedMemorySize, MH_SMEM);
  mh_kernel<<<32, 256, MH_SMEM, stream>>>(q, khi, klo, mhi, mlo);

  (void)hipFuncSetAttribute(reinterpret_cast<const void*>(&attn_kernel),
                            hipFuncAttributeMaxDynamicSharedMemorySize, SMEM_BYTES);
  attn_kernel<<<1024, 512, SMEM_BYTES, stream>>>(x, mhi, mlo, vT, soP, out);
}